// Round 16
// baseline (192.218 us; speedup 1.0000x reference)
//
#include <hip/hip_runtime.h>
#include <stdint.h>

#define HW 4096
#define CH 384
#define NB 8
#define K_SEL 128
#define BIG_DIST 1.0e7f
#define N_SENT 8100        // sentinel n for masked rows (> max real 7938)
#define PAGE 8192          // one 128x32 f16 tile = 8 KB
#define NKB 12             // 384 / 32
#define NRB 32             // 4096 / 128 (max panels)

typedef unsigned long long u64;
typedef _Float16 f16;
typedef _Float16 f16x8 __attribute__((ext_vector_type(8)));
typedef float f32x4 __attribute__((ext_vector_type(4)));

__device__ __forceinline__ u64 encode_di(float d, int idx) {
    // d >= 0 always, so float bits are order-isomorphic.
    return ((u64)__float_as_uint(d) << 32) | (unsigned)idx;
}

__device__ __forceinline__ void gl_lds16(const void* g, void* l) {
    __builtin_amdgcn_global_load_lds(
        (const __attribute__((address_space(1))) unsigned int*)g,
        (__attribute__((address_space(3))) unsigned int*)l, 16, 0, 0);
}

// XOR swizzle of a byte offset inside one 128x32 f16 page: spreads the
// 64B rows across banks so ds_read_b128 column-slices are <=2-way (free).
__device__ __forceinline__ int swz(int row, int bytecol) {
    return (row * 64 + bytecol) ^ ((row & 7) << 4);
}

// ------------------- stable compaction of valid indices + slot init
// grid (NB, 2), block 1024; thread t owns contiguous indices [4t, 4t+4).
__global__ __launch_bounds__(1024)
void compact_mask(const int* __restrict__ mask1, const int* __restrict__ mask2,
                  int* __restrict__ vidx1, int* __restrict__ vidx2,
                  int* __restrict__ cpos1, int* __restrict__ cpos2,
                  u64* __restrict__ slot1, u64* __restrict__ slot2,
                  int* __restrict__ cnts) {
    const int b = blockIdx.x, which = blockIdx.y;
    const int* m = (which ? mask2 : mask1) + (size_t)b * HW;
    int* vidx = (which ? vidx2 : vidx1) + (size_t)b * HW;
    int* cpos = (which ? cpos2 : cpos1) + (size_t)b * HW;
    u64* slot = (which ? slot2 : slot1) + (size_t)b * HW;
    const int tid = threadIdx.x;
    const int lane = tid & 63, wv = tid >> 6;

    const int base = tid * 4;
    int4 mm = *(const int4*)(m + base);
    int v0 = mm.x > 0, v1 = mm.y > 0, v2 = mm.z > 0, v3 = mm.w > 0;
    int sum = v0 + v1 + v2 + v3;

    int inc = sum;                       // wave inclusive scan
#pragma unroll
    for (int off = 1; off < 64; off <<= 1) {
        int o = __shfl_up(inc, off, 64);
        if (lane >= off) inc += o;
    }
    __shared__ int wtot[16], wbase[16];
    if (lane == 63) wtot[wv] = inc;
    __syncthreads();
    if (tid == 0) {
        int acc = 0;
        for (int w = 0; w < 16; ++w) { wbase[w] = acc; acc += wtot[w]; }
        cnts[b * 2 + which] = acc;
    }
    __syncthreads();
    int pos = wbase[wv] + inc - sum;     // stable exclusive prefix
    if (v0) { vidx[pos] = base;     cpos[base]     = pos; pos++; } else cpos[base]     = -1;
    if (v1) { vidx[pos] = base + 1; cpos[base + 1] = pos; pos++; } else cpos[base + 1] = -1;
    if (v2) { vidx[pos] = base + 2; cpos[base + 2] = pos; pos++; } else cpos[base + 2] = -1;
    if (v3) { vidx[pos] = base + 3; cpos[base + 3] = pos; pos++; } else cpos[base + 3] = -1;
    __syncthreads();
    const int cnt = wbase[15] + wtot[15];
    for (int t = cnt + tid; t < HW; t += 1024) vidx[t] = 0;
    for (int t = tid; t < HW; t += 1024) slot[t] = ~0ULL;
}

// ---------- single-pass prep: row in registers, 8-lane norm reduce, convert
// grid (NB*NRB, 2), block 1024. Thread t owns row t>>3 chunk kq=t&7:
// 12 float4 (48 f32) in registers -> one HBM read per row total.
__global__ __launch_bounds__(1024)
void prep_tiles(const float* __restrict__ f1, const float* __restrict__ f2,
                const int* __restrict__ vidx1, const int* __restrict__ vidx2,
                const int* __restrict__ cnts,
                float* __restrict__ sqc1, float* __restrict__ sqc2,
                char* __restrict__ tA, char* __restrict__ tB) {
    const int lin = blockIdx.x;           // b*NRB + rb
    const int rb = lin % NRB;
    const int b = lin / NRB;
    const int which = blockIdx.y;
    const int cnt = cnts[b * 2 + which];
    const int rowbase = rb * 128;
    if (rowbase >= cnt) return;           // panel entirely past the valid count

    const float* f = which ? f2 : f1;
    const int* vidx = (which ? vidx2 : vidx1) + (size_t)b * HW;
    float* sqc = which ? sqc2 : sqc1;
    char* pages = (which ? tB : tA) + (size_t)lin * NKB * 2 * PAGE;
    const size_t bb = (size_t)b * HW;

    const int tid = threadIdx.x;
    const int r = tid >> 3;               // local compact row 0..127
    const int kq = tid & 7;               // this thread's chunk within the row
    const int gr = rowbase + r;
    const int valid = gr < cnt;
    const int grow = vidx[gr];            // 0 for padding rows (harmless read)
    const float* rowp = f + (bb + grow) * CH + kq * 4;

    float4 x4[12];
    float s = 0.f;
#pragma unroll
    for (int kb = 0; kb < NKB; ++kb) {
        float4 v = *(const float4*)(rowp + kb * 32);
        x4[kb] = v;
        s += v.x * v.x + v.y * v.y + v.z * v.z + v.w * v.w;
    }
    // reduce over the 8 lanes owning this row (lanes differ in bits 0..2)
    s += __shfl_xor(s, 1, 64);
    s += __shfl_xor(s, 2, 64);
    s += __shfl_xor(s, 4, 64);
    float rinv = 1.0f / __fsqrt_rn(s);
    float s2 = 0.f;
#pragma unroll
    for (int kb = 0; kb < NKB; ++kb) {
        float4 v = x4[kb];
        float ax = v.x * rinv, ay = v.y * rinv, az = v.z * rinv, aw = v.w * rinv;
        s2 += ax * ax + ay * ay + az * az + aw * aw;
    }
    s2 += __shfl_xor(s2, 1, 64);
    s2 += __shfl_xor(s2, 2, 64);
    s2 += __shfl_xor(s2, 4, 64);
    if (kq == 0) sqc[bb + gr] = valid ? s2 : 0.f;

    const float rv = valid ? rinv : 0.f;  // pad rows -> zero tiles
    const int off = swz(r, kq * 8);
#pragma unroll
    for (int kb = 0; kb < NKB; ++kb) {
        char* hipg = pages + (size_t)kb * 2 * PAGE;
        char* lopg = hipg + PAGE;
        float4 v = x4[kb];
        float ax = v.x * rv, ay = v.y * rv, az = v.z * rv, aw = v.w * rv;
        f16 h0 = (f16)ax, h1 = (f16)ay, h2 = (f16)az, h3 = (f16)aw;
        f16 l0 = (f16)((ax - (float)h0) * 2048.0f);
        f16 l1 = (f16)((ay - (float)h1) * 2048.0f);
        f16 l2 = (f16)((az - (float)h2) * 2048.0f);
        f16 l3 = (f16)((aw - (float)h3) * 2048.0f);
        union { f16 h[4]; uint2 u; } H = {{h0, h1, h2, h3}};
        union { f16 h[4]; uint2 u; } L = {{l0, l1, l2, l3}};
        *(uint2*)(hipg + off) = H.u;
        *(uint2*)(lopg + off) = L.u;
    }
}

// ----------------------------------------- fused split-MFMA GEMM + argmin
// (r12 structure; occupancy bumped to 4 blocks/CU: VGPR 84 <= 128/wave,
//  LDS 4 x 34KB = 136KB <= 160KB)
__global__ __launch_bounds__(256, 4)
void gemm_argmin(const char* __restrict__ tA, const char* __restrict__ tB,
                 const float* __restrict__ sqc1, const float* __restrict__ sqc2,
                 const int* __restrict__ vidx1, const int* __restrict__ vidx2,
                 const int* __restrict__ cnts,
                 u64* __restrict__ slot1, u64* __restrict__ slot2) {
    __shared__ __align__(16) char smem[4 * PAGE];   // Ahi Alo Bhi Blo
    __shared__ u64 rowSlot[128];
    __shared__ u64 colSlot[128];

    const int b = blockIdx.y;
    const int tid = threadIdx.x;

    const int cnt1 = cnts[b * 2], cnt2 = cnts[b * 2 + 1];
    const int nby = (cnt1 + 127) >> 7;
    const int nbx = (cnt2 + 127) >> 7;
    const int nact = nby * nbx;

    // bijective split of [0,nact) into 8 XCD chunks (handles nact%8 != 0)
    const int xcd = blockIdx.x & 7;
    const int s = blockIdx.x >> 3;        // slot within this XCD, 0..127
    const int q = nact >> 3, r8 = nact & 7;
    const int csz = q + (xcd < r8 ? 1 : 0);
    if (s >= csz) return;
    const int L = (xcd < r8 ? xcd * (q + 1) : r8 * (q + 1) + (xcd - r8) * q) + s;
    const int bx = L / nby;               // bx-outer: chunk = few B panels
    const int by = L - bx * nby;          // co-resident blocks share B panel
    const int brow = by * 128, bcol = bx * 128;

    // slot init early: first K-step barrier orders it before any epilogue use
    if (tid < 128) { rowSlot[tid] = ~0ULL; colSlot[tid] = ~0ULL; }

    const char* Abase = tA + (size_t)(b * NRB + by) * NKB * 2 * PAGE;
    const char* Bbase = tB + (size_t)(b * NRB + bx) * NKB * 2 * PAGE;

    const int wv = tid >> 6, lane = tid & 63;
    const int wr = wv >> 1, wc = wv & 1;   // wave grid 2x2, wave tile 64x64
    const int r0 = lane & 15, kc = lane >> 4;

    int aoff[4], boff[4];
#pragma unroll
    for (int m = 0; m < 4; ++m) {
        int ra = wr * 64 + m * 16 + r0;
        aoff[m] = swz(ra, kc * 16);
        int rb_ = wc * 64 + m * 16 + r0;
        boff[m] = swz(rb_, kc * 16);
    }

    f32x4 acc[4][4];
    f32x4 zero = {0.f, 0.f, 0.f, 0.f};
#pragma unroll
    for (int m = 0; m < 4; ++m)
#pragma unroll
        for (int n = 0; n < 4; ++n) acc[m][n] = zero;

    const int stg = wv * 1024;            // wave-uniform LDS chunk base
    const int src_l = stg + lane * 16;
    const f16 K2048 = (f16)2048.0f;

    for (int kb = 0; kb < NKB; ++kb) {
        const char* gA = Abase + (size_t)kb * 2 * PAGE;
        const char* gB = Bbase + (size_t)kb * 2 * PAGE;
#pragma unroll
        for (int p = 0; p < 4; ++p) {
            gl_lds16(gA + p * 4096 + src_l, smem + p * 4096 + stg);
            gl_lds16(gB + p * 4096 + src_l, smem + 16384 + p * 4096 + stg);
        }
        asm volatile("s_waitcnt vmcnt(0)" ::: "memory");
        __syncthreads();

        f16x8 bh[4], bl[4];
#pragma unroll
        for (int n = 0; n < 4; ++n) {
            bh[n] = *(const f16x8*)(smem + 2 * PAGE + boff[n]);
            bl[n] = *(const f16x8*)(smem + 3 * PAGE + boff[n]);
        }
#pragma unroll
        for (int m = 0; m < 4; ++m) {
            f16x8 ah = *(const f16x8*)(smem + aoff[m]);
            f16x8 al = *(const f16x8*)(smem + PAGE + aoff[m]);
            f16x8 ah2 = ah * K2048;       // exact (power-of-two scale)
#pragma unroll
            for (int n = 0; n < 4; ++n) {
                acc[m][n] = __builtin_amdgcn_mfma_f32_16x16x32_f16(ah2, bh[n], acc[m][n], 0, 0, 0);
                acc[m][n] = __builtin_amdgcn_mfma_f32_16x16x32_f16(ah, bl[n], acc[m][n], 0, 0, 0);
                acc[m][n] = __builtin_amdgcn_mfma_f32_16x16x32_f16(al, bh[n], acc[m][n], 0, 0, 0);
            }
        }
        __syncthreads();
    }

    // ---------------- epilogue: d + row/col argmin (u64-encoded, orig idx)
    const size_t bb = (size_t)b * HW;
    const int rfrag = kc * 4;              // C/D: row = (lane>>4)*4 + reg, col = lane&15
    float s1v[4][4];
    int o1v[4][4], val1[4][4];
#pragma unroll
    for (int m = 0; m < 4; ++m) {
        int rr = brow + wr * 64 + m * 16 + rfrag;   // compact row
        float4 sv = *(const float4*)(sqc1 + bb + rr);
        int4 ov = *(const int4*)(vidx1 + bb + rr);
        s1v[m][0] = sv.x; s1v[m][1] = sv.y; s1v[m][2] = sv.z; s1v[m][3] = sv.w;
        o1v[m][0] = ov.x; o1v[m][1] = ov.y; o1v[m][2] = ov.z; o1v[m][3] = ov.w;
#pragma unroll
        for (int j = 0; j < 4; ++j) val1[m][j] = (rr + j) < cnt1;
    }
    float s2v[4];
    int o2v[4], val2[4];
#pragma unroll
    for (int n = 0; n < 4; ++n) {
        int cc = bcol + wc * 64 + n * 16 + r0;      // compact col
        s2v[n] = sqc2[bb + cc];
        o2v[n] = vidx2[bb + cc];
        val2[n] = cc < cnt2;
    }

    u64 cbest[4] = {~0ULL, ~0ULL, ~0ULL, ~0ULL};
#pragma unroll
    for (int m = 0; m < 4; ++m) {
#pragma unroll
        for (int j = 0; j < 4; ++j) {
            u64 rbest = ~0ULL;
#pragma unroll
            for (int n = 0; n < 4; ++n) {
                float d;
                if (val1[m][j] && val2[n]) {
                    float dot = acc[m][n][j] * (1.0f / 2048.0f);
                    float t = __fmul_rn(2.0f, dot);
                    float d2 = __fsub_rn(__fadd_rn(s1v[m][j], s2v[n]), t);
                    d = __fsqrt_rn(fmaxf(d2, 0.0f));
                } else {
                    d = BIG_DIST;
                }
                u64 er = encode_di(d, o2v[n]);      // original col index
                u64 ec = encode_di(d, o1v[m][j]);   // original row index
                if (er < rbest) rbest = er;
                if (ec < cbest[n]) cbest[n] = ec;
            }
            atomicMin(&rowSlot[wr * 64 + m * 16 + rfrag + j], rbest);
        }
    }
#pragma unroll
    for (int n = 0; n < 4; ++n)
        atomicMin(&colSlot[wc * 64 + n * 16 + r0], cbest[n]);
    __syncthreads();

    if (tid < 128) atomicMin(&slot1[bb + brow + tid], rowSlot[tid]);
    else           atomicMin(&slot2[bb + bcol + tid - 128], colSlot[tid - 128]);
}

// ------ match lookup through compaction maps (masked/empty -> 0, as ref)
__device__ __forceinline__ int get_match(const u64* __restrict__ slot,
                                         const int* __restrict__ cpos,
                                         size_t bb, int t) {
    int p = cpos[bb + t];
    if (p < 0) return 0;
    u64 sv = slot[bb + p];
    return (sv != ~0ULL) ? (int)(unsigned)(sv & 0xFFFFFFFFu) : 0;
}

// -------- top-K via exact INTEGER coord-error: diff = sqrt(dx^2+dy^2) with
// integer dx,dy -> n = dx^2+dy^2 <= 7938 is exact; f32 sqrt is monotone-
// injective over these n, so (n, t) ordering == reference (diff, t) ordering.
// Key = (n << 12) | t (25 bits). 2 radix passes: 13-bit n, then 12-bit t.
__global__ __launch_bounds__(1024)
void topk_output(const u64* __restrict__ slot1, const u64* __restrict__ slot2,
                 const int* __restrict__ cpos1, const int* __restrict__ cpos2,
                 const int* __restrict__ mask1, const int* __restrict__ mask2,
                 const int* __restrict__ backup1, const int* __restrict__ backup2,
                 int* __restrict__ out) {
    __shared__ int nkey[HW];             // 16 KB
    __shared__ int hist[8192];           // 32 KB
    __shared__ int sel[K_SEL];
    __shared__ int wtot[16], wbase[16];
    __shared__ int cnt, selc, sn, st;
    const int b = blockIdx.x;
    const int dir = blockIdx.y;
    const u64* slotF = dir ? slot2 : slot1;
    const u64* slotB = dir ? slot1 : slot2;
    const int* cposF = dir ? cpos2 : cpos1;
    const int* cposB = dir ? cpos1 : cpos2;
    const int* maskS = dir ? mask2 : mask1;
    const int* maskD = dir ? mask1 : mask2;
    const int* backup = dir ? backup2 : backup1;
    const int tid = threadIdx.x;
    const int lane = tid & 63, wv = tid >> 6;
    const size_t bb = (size_t)b * HW;

    if (tid == 0) { cnt = 0; selc = 0; }
    for (int h = tid; h < 8192; h += 1024) hist[h] = 0;
    __syncthreads();

    int local = 0;
    for (int t = tid; t < HW; t += 1024) {
        int mf = get_match(slotF, cposF, bb, t);
        int dv = maskD[bb + mf];
        int cyc = get_match(slotB, cposB, bb, mf);
        int dx = (cyc >> 6) - (t >> 6);
        int dy = (cyc & 63) - (t & 63);
        int ms = maskS[bb + t];
        int n = (ms > 0 && dv > 0) ? (dx * dx + dy * dy) : N_SENT;
        nkey[t] = (n << 12) | t;
        local += (ms > 0) ? 1 : 0;
        atomicAdd(&hist[n], 1);
    }
    atomicAdd(&cnt, local);
    __syncthreads();

    // ---- pass 1: find pivot bucket sn containing rank 127 (8 buckets/thread)
    int rank = 127;
    {
        const int hbase = tid * 8;
        int ssum = 0;
#pragma unroll
        for (int i = 0; i < 8; ++i) ssum += hist[hbase + i];
        int inc = ssum;
#pragma unroll
        for (int off = 1; off < 64; off <<= 1) {
            int o = __shfl_up(inc, off, 64);
            if (lane >= off) inc += o;
        }
        if (lane == 63) wtot[wv] = inc;
        __syncthreads();
        if (tid == 0) {
            int acc = 0;
            for (int w = 0; w < 16; ++w) { wbase[w] = acc; acc += wtot[w]; }
        }
        __syncthreads();
        int pre = wbase[wv] + inc - ssum;
        if (rank >= pre && rank < pre + ssum) {
            int rr = rank - pre;
            for (int i = 0; i < 8; ++i) {
                int h = hist[hbase + i];
                if (rr < h) { sn = hbase + i; st = rr; break; }
                rr -= h;
            }
        }
        __syncthreads();
    }
    const int npiv = sn;
    rank = st;                            // rank within the n==npiv bucket
    __syncthreads();

    // ---- pass 2: rank-th smallest t among keys with n == npiv (4 bkt/thread)
    for (int h = tid; h < 4096; h += 1024) hist[h] = 0;
    __syncthreads();
    for (int t = tid; t < HW; t += 1024)
        if ((nkey[t] >> 12) == npiv) hist[t] = 1;   // t unique -> 0/1 hist
    __syncthreads();
    {
        const int hbase = tid * 4;
        int ssum = hist[hbase] + hist[hbase + 1] + hist[hbase + 2] + hist[hbase + 3];
        int inc = ssum;
#pragma unroll
        for (int off = 1; off < 64; off <<= 1) {
            int o = __shfl_up(inc, off, 64);
            if (lane >= off) inc += o;
        }
        if (lane == 63) wtot[wv] = inc;
        __syncthreads();
        if (tid == 0) {
            int acc = 0;
            for (int w = 0; w < 16; ++w) { wbase[w] = acc; acc += wtot[w]; }
        }
        __syncthreads();
        int pre = wbase[wv] + inc - ssum;
        if (rank >= pre && rank < pre + ssum) {
            int rr = rank - pre;
            for (int i = 0; i < 4; ++i) {
                int h = hist[hbase + i];
                if (rr < h) { st = hbase + i; break; }
                rr -= h;
            }
        }
        __syncthreads();
    }
    const int pivot = (npiv << 12) | st;  // exact rank-127 key

    for (int t = tid; t < HW; t += 1024) {
        int k = nkey[t];
        if (k <= pivot) { int p = atomicAdd(&selc, 1); if (p < K_SEL) sel[p] = k; }
    }
    __syncthreads();

    // bitonic sort of the 128 selected keys (ascending; exactly 128 <= pivot)
    for (unsigned kk = 2; kk <= K_SEL; kk <<= 1) {
        for (unsigned j = kk >> 1; j > 0; j >>= 1) {
            if (tid < K_SEL) {
                unsigned ixj = tid ^ j;
                if (ixj > tid) {
                    int a = sel[tid], c = sel[ixj];
                    bool up = ((tid & kk) == 0);
                    if ((a > c) == up) { sel[tid] = c; sel[ixj] = a; }
                }
            }
            __syncthreads();
        }
    }

    if (tid < K_SEL) {
        int c;
        if (cnt >= K_SEL) c = sel[tid] & 0xFFF;
        else c = backup[b * K_SEL + tid];
        int cm = get_match(slotF, cposF, bb, c);
        int* o = out + dir * (NB * K_SEL * 2);
        o[(b * K_SEL + tid) * 2 + 0] = c;
        o[(b * K_SEL + tid) * 2 + 1] = cm;
    }
}

// ---------------------------------------------------------------------------
extern "C" void kernel_launch(void* const* d_in, const int* in_sizes, int n_in,
                              void* d_out, int out_size, void* d_ws, size_t ws_size,
                              hipStream_t stream) {
    const float* f1 = (const float*)d_in[0];
    const float* f2 = (const float*)d_in[1];
    const int* mask1 = (const int*)d_in[2];
    const int* mask2 = (const int*)d_in[3];
    const int* backup1 = (const int*)d_in[4];
    const int* backup2 = (const int*)d_in[5];
    int* out = (int*)d_out;

    char* ws = (char*)d_ws;
    char* tA = ws;                    ws += (size_t)NB * NRB * NKB * 2 * PAGE;
    char* tB = ws;                    ws += (size_t)NB * NRB * NKB * 2 * PAGE;
    u64* slot1 = (u64*)ws;            ws += (size_t)NB * HW * 8;
    u64* slot2 = (u64*)ws;            ws += (size_t)NB * HW * 8;
    float* sqc1 = (float*)ws;         ws += (size_t)NB * HW * 4;
    float* sqc2 = (float*)ws;         ws += (size_t)NB * HW * 4;
    int* vidx1 = (int*)ws;            ws += (size_t)NB * HW * 4;
    int* vidx2 = (int*)ws;            ws += (size_t)NB * HW * 4;
    int* cpos1 = (int*)ws;            ws += (size_t)NB * HW * 4;
    int* cpos2 = (int*)ws;            ws += (size_t)NB * HW * 4;
    int* cnts = (int*)ws;             ws += 256;

    compact_mask<<<dim3(NB, 2), 1024, 0, stream>>>(mask1, mask2,
                                                   vidx1, vidx2, cpos1, cpos2,
                                                   slot1, slot2, cnts);
    prep_tiles<<<dim3(NB * NRB, 2), 1024, 0, stream>>>(f1, f2, vidx1, vidx2,
                                                       cnts, sqc1, sqc2, tA, tB);
    gemm_argmin<<<dim3(1024, NB), 256, 0, stream>>>(tA, tB, sqc1, sqc2,
                                                    vidx1, vidx2, cnts,
                                                    slot1, slot2);
    topk_output<<<dim3(NB, 2), 1024, 0, stream>>>(slot1, slot2, cpos1, cpos2,
                                                  mask1, mask2, backup1, backup2,
                                                  out);
}

// Round 17
// 150.180 us; speedup vs baseline: 1.2799x; 1.2799x over previous
//
#include <hip/hip_runtime.h>
#include <stdint.h>

#define HW 4096
#define CH 384
#define NB 8
#define K_SEL 128
#define BIG_DIST 1.0e7f
#define N_SENT 8100        // sentinel n for masked rows (> max real 7938)
#define PAGE 8192          // one 128x32 f16 tile = 8 KB
#define NKB 12             // 384 / 32
#define NRB 32             // 4096 / 128 (max panels)

typedef unsigned long long u64;
typedef _Float16 f16;
typedef _Float16 f16x8 __attribute__((ext_vector_type(8)));
typedef float f32x4 __attribute__((ext_vector_type(4)));

__device__ __forceinline__ u64 encode_di(float d, int idx) {
    // d >= 0 always, so float bits are order-isomorphic.
    return ((u64)__float_as_uint(d) << 32) | (unsigned)idx;
}

__device__ __forceinline__ void gl_lds16(const void* g, void* l) {
    __builtin_amdgcn_global_load_lds(
        (const __attribute__((address_space(1))) unsigned int*)g,
        (__attribute__((address_space(3))) unsigned int*)l, 16, 0, 0);
}

// XOR swizzle of a byte offset inside one 128x32 f16 page: spreads the
// 64B rows across banks so ds_read_b128 column-slices are <=2-way (free).
__device__ __forceinline__ int swz(int row, int bytecol) {
    return (row * 64 + bytecol) ^ ((row & 7) << 4);
}

// ------------------- stable compaction of valid indices + slot init
// grid (NB, 2), block 1024; thread t owns contiguous indices [4t, 4t+4).
__global__ __launch_bounds__(1024)
void compact_mask(const int* __restrict__ mask1, const int* __restrict__ mask2,
                  int* __restrict__ vidx1, int* __restrict__ vidx2,
                  int* __restrict__ cpos1, int* __restrict__ cpos2,
                  u64* __restrict__ slot1, u64* __restrict__ slot2,
                  int* __restrict__ cnts) {
    const int b = blockIdx.x, which = blockIdx.y;
    const int* m = (which ? mask2 : mask1) + (size_t)b * HW;
    int* vidx = (which ? vidx2 : vidx1) + (size_t)b * HW;
    int* cpos = (which ? cpos2 : cpos1) + (size_t)b * HW;
    u64* slot = (which ? slot2 : slot1) + (size_t)b * HW;
    const int tid = threadIdx.x;
    const int lane = tid & 63, wv = tid >> 6;

    const int base = tid * 4;
    int4 mm = *(const int4*)(m + base);
    int v0 = mm.x > 0, v1 = mm.y > 0, v2 = mm.z > 0, v3 = mm.w > 0;
    int sum = v0 + v1 + v2 + v3;

    int inc = sum;                       // wave inclusive scan
#pragma unroll
    for (int off = 1; off < 64; off <<= 1) {
        int o = __shfl_up(inc, off, 64);
        if (lane >= off) inc += o;
    }
    __shared__ int wtot[16], wbase[16];
    if (lane == 63) wtot[wv] = inc;
    __syncthreads();
    if (tid == 0) {
        int acc = 0;
        for (int w = 0; w < 16; ++w) { wbase[w] = acc; acc += wtot[w]; }
        cnts[b * 2 + which] = acc;
    }
    __syncthreads();
    int pos = wbase[wv] + inc - sum;     // stable exclusive prefix
    if (v0) { vidx[pos] = base;     cpos[base]     = pos; pos++; } else cpos[base]     = -1;
    if (v1) { vidx[pos] = base + 1; cpos[base + 1] = pos; pos++; } else cpos[base + 1] = -1;
    if (v2) { vidx[pos] = base + 2; cpos[base + 2] = pos; pos++; } else cpos[base + 2] = -1;
    if (v3) { vidx[pos] = base + 3; cpos[base + 3] = pos; pos++; } else cpos[base + 3] = -1;
    __syncthreads();
    const int cnt = wbase[15] + wtot[15];
    for (int t = cnt + tid; t < HW; t += 1024) vidx[t] = 0;
    for (int t = tid; t < HW; t += 1024) slot[t] = ~0ULL;
}

// ---------- single-pass prep: row in registers, 8-lane norm reduce, convert
// grid (NB*NRB, 2), block 1024. Thread t owns row t>>3 chunk kq=t&7:
// 12 float4 (48 f32) in registers -> one HBM read per row total.
__global__ __launch_bounds__(1024)
void prep_tiles(const float* __restrict__ f1, const float* __restrict__ f2,
                const int* __restrict__ vidx1, const int* __restrict__ vidx2,
                const int* __restrict__ cnts,
                float* __restrict__ sqc1, float* __restrict__ sqc2,
                char* __restrict__ tA, char* __restrict__ tB) {
    const int lin = blockIdx.x;           // b*NRB + rb
    const int rb = lin % NRB;
    const int b = lin / NRB;
    const int which = blockIdx.y;
    const int cnt = cnts[b * 2 + which];
    const int rowbase = rb * 128;
    if (rowbase >= cnt) return;           // panel entirely past the valid count

    const float* f = which ? f2 : f1;
    const int* vidx = (which ? vidx2 : vidx1) + (size_t)b * HW;
    float* sqc = which ? sqc2 : sqc1;
    char* pages = (which ? tB : tA) + (size_t)lin * NKB * 2 * PAGE;
    const size_t bb = (size_t)b * HW;

    const int tid = threadIdx.x;
    const int r = tid >> 3;               // local compact row 0..127
    const int kq = tid & 7;               // this thread's chunk within the row
    const int gr = rowbase + r;
    const int valid = gr < cnt;
    const int grow = vidx[gr];            // 0 for padding rows (harmless read)
    const float* rowp = f + (bb + grow) * CH + kq * 4;

    float4 x4[12];
    float s = 0.f;
#pragma unroll
    for (int kb = 0; kb < NKB; ++kb) {
        float4 v = *(const float4*)(rowp + kb * 32);
        x4[kb] = v;
        s += v.x * v.x + v.y * v.y + v.z * v.z + v.w * v.w;
    }
    // reduce over the 8 lanes owning this row (lanes differ in bits 0..2)
    s += __shfl_xor(s, 1, 64);
    s += __shfl_xor(s, 2, 64);
    s += __shfl_xor(s, 4, 64);
    float rinv = 1.0f / __fsqrt_rn(s);
    float s2 = 0.f;
#pragma unroll
    for (int kb = 0; kb < NKB; ++kb) {
        float4 v = x4[kb];
        float ax = v.x * rinv, ay = v.y * rinv, az = v.z * rinv, aw = v.w * rinv;
        s2 += ax * ax + ay * ay + az * az + aw * aw;
    }
    s2 += __shfl_xor(s2, 1, 64);
    s2 += __shfl_xor(s2, 2, 64);
    s2 += __shfl_xor(s2, 4, 64);
    if (kq == 0) sqc[bb + gr] = valid ? s2 : 0.f;

    const float rv = valid ? rinv : 0.f;  // pad rows -> zero tiles
    const int off = swz(r, kq * 8);
#pragma unroll
    for (int kb = 0; kb < NKB; ++kb) {
        char* hipg = pages + (size_t)kb * 2 * PAGE;
        char* lopg = hipg + PAGE;
        float4 v = x4[kb];
        float ax = v.x * rv, ay = v.y * rv, az = v.z * rv, aw = v.w * rv;
        f16 h0 = (f16)ax, h1 = (f16)ay, h2 = (f16)az, h3 = (f16)aw;
        f16 l0 = (f16)((ax - (float)h0) * 2048.0f);
        f16 l1 = (f16)((ay - (float)h1) * 2048.0f);
        f16 l2 = (f16)((az - (float)h2) * 2048.0f);
        f16 l3 = (f16)((aw - (float)h3) * 2048.0f);
        union { f16 h[4]; uint2 u; } H = {{h0, h1, h2, h3}};
        union { f16 h[4]; uint2 u; } L = {{l0, l1, l2, l3}};
        *(uint2*)(hipg + off) = H.u;
        *(uint2*)(lopg + off) = L.u;
    }
}

// ----------------------------------------- fused split-MFMA GEMM + argmin
// (frozen: r12's measured-best -- 128^2 tile, single x2048 accumulator,
//  __launch_bounds__(256,3): 84 VGPR no-spill / 3 blocks/CU. (256,4) was
//  tried r16: 64-VGPR cap -> scratch spills, WRITE_SIZE 4MB->152MB, -40%.)
__global__ __launch_bounds__(256, 3)
void gemm_argmin(const char* __restrict__ tA, const char* __restrict__ tB,
                 const float* __restrict__ sqc1, const float* __restrict__ sqc2,
                 const int* __restrict__ vidx1, const int* __restrict__ vidx2,
                 const int* __restrict__ cnts,
                 u64* __restrict__ slot1, u64* __restrict__ slot2) {
    __shared__ __align__(16) char smem[4 * PAGE];   // Ahi Alo Bhi Blo
    __shared__ u64 rowSlot[128];
    __shared__ u64 colSlot[128];

    const int b = blockIdx.y;
    const int tid = threadIdx.x;

    const int cnt1 = cnts[b * 2], cnt2 = cnts[b * 2 + 1];
    const int nby = (cnt1 + 127) >> 7;
    const int nbx = (cnt2 + 127) >> 7;
    const int nact = nby * nbx;

    // bijective split of [0,nact) into 8 XCD chunks (handles nact%8 != 0)
    const int xcd = blockIdx.x & 7;
    const int s = blockIdx.x >> 3;        // slot within this XCD, 0..127
    const int q = nact >> 3, r8 = nact & 7;
    const int csz = q + (xcd < r8 ? 1 : 0);
    if (s >= csz) return;
    const int L = (xcd < r8 ? xcd * (q + 1) : r8 * (q + 1) + (xcd - r8) * q) + s;
    const int bx = L / nby;               // bx-outer: chunk = few B panels
    const int by = L - bx * nby;          // co-resident blocks share B panel
    const int brow = by * 128, bcol = bx * 128;

    // slot init early: first K-step barrier orders it before any epilogue use
    if (tid < 128) { rowSlot[tid] = ~0ULL; colSlot[tid] = ~0ULL; }

    const char* Abase = tA + (size_t)(b * NRB + by) * NKB * 2 * PAGE;
    const char* Bbase = tB + (size_t)(b * NRB + bx) * NKB * 2 * PAGE;

    const int wv = tid >> 6, lane = tid & 63;
    const int wr = wv >> 1, wc = wv & 1;   // wave grid 2x2, wave tile 64x64
    const int r0 = lane & 15, kc = lane >> 4;

    int aoff[4], boff[4];
#pragma unroll
    for (int m = 0; m < 4; ++m) {
        int ra = wr * 64 + m * 16 + r0;
        aoff[m] = swz(ra, kc * 16);
        int rb_ = wc * 64 + m * 16 + r0;
        boff[m] = swz(rb_, kc * 16);
    }

    f32x4 acc[4][4];
    f32x4 zero = {0.f, 0.f, 0.f, 0.f};
#pragma unroll
    for (int m = 0; m < 4; ++m)
#pragma unroll
        for (int n = 0; n < 4; ++n) acc[m][n] = zero;

    const int stg = wv * 1024;            // wave-uniform LDS chunk base
    const int src_l = stg + lane * 16;
    const f16 K2048 = (f16)2048.0f;

    for (int kb = 0; kb < NKB; ++kb) {
        const char* gA = Abase + (size_t)kb * 2 * PAGE;
        const char* gB = Bbase + (size_t)kb * 2 * PAGE;
#pragma unroll
        for (int p = 0; p < 4; ++p) {
            gl_lds16(gA + p * 4096 + src_l, smem + p * 4096 + stg);
            gl_lds16(gB + p * 4096 + src_l, smem + 16384 + p * 4096 + stg);
        }
        asm volatile("s_waitcnt vmcnt(0)" ::: "memory");
        __syncthreads();

        f16x8 bh[4], bl[4];
#pragma unroll
        for (int n = 0; n < 4; ++n) {
            bh[n] = *(const f16x8*)(smem + 2 * PAGE + boff[n]);
            bl[n] = *(const f16x8*)(smem + 3 * PAGE + boff[n]);
        }
#pragma unroll
        for (int m = 0; m < 4; ++m) {
            f16x8 ah = *(const f16x8*)(smem + aoff[m]);
            f16x8 al = *(const f16x8*)(smem + PAGE + aoff[m]);
            f16x8 ah2 = ah * K2048;       // exact (power-of-two scale)
#pragma unroll
            for (int n = 0; n < 4; ++n) {
                acc[m][n] = __builtin_amdgcn_mfma_f32_16x16x32_f16(ah2, bh[n], acc[m][n], 0, 0, 0);
                acc[m][n] = __builtin_amdgcn_mfma_f32_16x16x32_f16(ah, bl[n], acc[m][n], 0, 0, 0);
                acc[m][n] = __builtin_amdgcn_mfma_f32_16x16x32_f16(al, bh[n], acc[m][n], 0, 0, 0);
            }
        }
        __syncthreads();
    }

    // ---------------- epilogue: d + row/col argmin (u64-encoded, orig idx)
    const size_t bb = (size_t)b * HW;
    const int rfrag = kc * 4;              // C/D: row = (lane>>4)*4 + reg, col = lane&15
    float s1v[4][4];
    int o1v[4][4], val1[4][4];
#pragma unroll
    for (int m = 0; m < 4; ++m) {
        int rr = brow + wr * 64 + m * 16 + rfrag;   // compact row
        float4 sv = *(const float4*)(sqc1 + bb + rr);
        int4 ov = *(const int4*)(vidx1 + bb + rr);
        s1v[m][0] = sv.x; s1v[m][1] = sv.y; s1v[m][2] = sv.z; s1v[m][3] = sv.w;
        o1v[m][0] = ov.x; o1v[m][1] = ov.y; o1v[m][2] = ov.z; o1v[m][3] = ov.w;
#pragma unroll
        for (int j = 0; j < 4; ++j) val1[m][j] = (rr + j) < cnt1;
    }
    float s2v[4];
    int o2v[4], val2[4];
#pragma unroll
    for (int n = 0; n < 4; ++n) {
        int cc = bcol + wc * 64 + n * 16 + r0;      // compact col
        s2v[n] = sqc2[bb + cc];
        o2v[n] = vidx2[bb + cc];
        val2[n] = cc < cnt2;
    }

    u64 cbest[4] = {~0ULL, ~0ULL, ~0ULL, ~0ULL};
#pragma unroll
    for (int m = 0; m < 4; ++m) {
#pragma unroll
        for (int j = 0; j < 4; ++j) {
            u64 rbest = ~0ULL;
#pragma unroll
            for (int n = 0; n < 4; ++n) {
                float d;
                if (val1[m][j] && val2[n]) {
                    float dot = acc[m][n][j] * (1.0f / 2048.0f);
                    float t = __fmul_rn(2.0f, dot);
                    float d2 = __fsub_rn(__fadd_rn(s1v[m][j], s2v[n]), t);
                    d = __fsqrt_rn(fmaxf(d2, 0.0f));
                } else {
                    d = BIG_DIST;
                }
                u64 er = encode_di(d, o2v[n]);      // original col index
                u64 ec = encode_di(d, o1v[m][j]);   // original row index
                if (er < rbest) rbest = er;
                if (ec < cbest[n]) cbest[n] = ec;
            }
            atomicMin(&rowSlot[wr * 64 + m * 16 + rfrag + j], rbest);
        }
    }
#pragma unroll
    for (int n = 0; n < 4; ++n)
        atomicMin(&colSlot[wc * 64 + n * 16 + r0], cbest[n]);
    __syncthreads();

    if (tid < 128) atomicMin(&slot1[bb + brow + tid], rowSlot[tid]);
    else           atomicMin(&slot2[bb + bcol + tid - 128], colSlot[tid - 128]);
}

// ------ match lookup through compaction maps (masked/empty -> 0, as ref)
__device__ __forceinline__ int get_match(const u64* __restrict__ slot,
                                         const int* __restrict__ cpos,
                                         size_t bb, int t) {
    int p = cpos[bb + t];
    if (p < 0) return 0;
    u64 sv = slot[bb + p];
    return (sv != ~0ULL) ? (int)(unsigned)(sv & 0xFFFFFFFFu) : 0;
}

// -------- top-K via exact INTEGER coord-error: diff = sqrt(dx^2+dy^2) with
// integer dx,dy -> n = dx^2+dy^2 <= 7938 is exact; f32 sqrt is monotone-
// injective over these n, so (n, t) ordering == reference (diff, t) ordering.
// Key = (n << 12) | t (25 bits). 2 radix passes: 13-bit n, then 12-bit t.
__global__ __launch_bounds__(1024)
void topk_output(const u64* __restrict__ slot1, const u64* __restrict__ slot2,
                 const int* __restrict__ cpos1, const int* __restrict__ cpos2,
                 const int* __restrict__ mask1, const int* __restrict__ mask2,
                 const int* __restrict__ backup1, const int* __restrict__ backup2,
                 int* __restrict__ out) {
    __shared__ int nkey[HW];             // 16 KB
    __shared__ int hist[8192];           // 32 KB
    __shared__ int sel[K_SEL];
    __shared__ int wtot[16], wbase[16];
    __shared__ int cnt, selc, sn, st;
    const int b = blockIdx.x;
    const int dir = blockIdx.y;
    const u64* slotF = dir ? slot2 : slot1;
    const u64* slotB = dir ? slot1 : slot2;
    const int* cposF = dir ? cpos2 : cpos1;
    const int* cposB = dir ? cpos1 : cpos2;
    const int* maskS = dir ? mask2 : mask1;
    const int* maskD = dir ? mask1 : mask2;
    const int* backup = dir ? backup2 : backup1;
    const int tid = threadIdx.x;
    const int lane = tid & 63, wv = tid >> 6;
    const size_t bb = (size_t)b * HW;

    if (tid == 0) { cnt = 0; selc = 0; }
    for (int h = tid; h < 8192; h += 1024) hist[h] = 0;
    __syncthreads();

    int local = 0;
    for (int t = tid; t < HW; t += 1024) {
        int mf = get_match(slotF, cposF, bb, t);
        int dv = maskD[bb + mf];
        int cyc = get_match(slotB, cposB, bb, mf);
        int dx = (cyc >> 6) - (t >> 6);
        int dy = (cyc & 63) - (t & 63);
        int ms = maskS[bb + t];
        int n = (ms > 0 && dv > 0) ? (dx * dx + dy * dy) : N_SENT;
        nkey[t] = (n << 12) | t;
        local += (ms > 0) ? 1 : 0;
        atomicAdd(&hist[n], 1);
    }
    atomicAdd(&cnt, local);
    __syncthreads();

    // ---- pass 1: find pivot bucket sn containing rank 127 (8 buckets/thread)
    int rank = 127;
    {
        const int hbase = tid * 8;
        int ssum = 0;
#pragma unroll
        for (int i = 0; i < 8; ++i) ssum += hist[hbase + i];
        int inc = ssum;
#pragma unroll
        for (int off = 1; off < 64; off <<= 1) {
            int o = __shfl_up(inc, off, 64);
            if (lane >= off) inc += o;
        }
        if (lane == 63) wtot[wv] = inc;
        __syncthreads();
        if (tid == 0) {
            int acc = 0;
            for (int w = 0; w < 16; ++w) { wbase[w] = acc; acc += wtot[w]; }
        }
        __syncthreads();
        int pre = wbase[wv] + inc - ssum;
        if (rank >= pre && rank < pre + ssum) {
            int rr = rank - pre;
            for (int i = 0; i < 8; ++i) {
                int h = hist[hbase + i];
                if (rr < h) { sn = hbase + i; st = rr; break; }
                rr -= h;
            }
        }
        __syncthreads();
    }
    const int npiv = sn;
    rank = st;                            // rank within the n==npiv bucket
    __syncthreads();

    // ---- pass 2: rank-th smallest t among keys with n == npiv (4 bkt/thread)
    for (int h = tid; h < 4096; h += 1024) hist[h] = 0;
    __syncthreads();
    for (int t = tid; t < HW; t += 1024)
        if ((nkey[t] >> 12) == npiv) hist[t] = 1;   // t unique -> 0/1 hist
    __syncthreads();
    {
        const int hbase = tid * 4;
        int ssum = hist[hbase] + hist[hbase + 1] + hist[hbase + 2] + hist[hbase + 3];
        int inc = ssum;
#pragma unroll
        for (int off = 1; off < 64; off <<= 1) {
            int o = __shfl_up(inc, off, 64);
            if (lane >= off) inc += o;
        }
        if (lane == 63) wtot[wv] = inc;
        __syncthreads();
        if (tid == 0) {
            int acc = 0;
            for (int w = 0; w < 16; ++w) { wbase[w] = acc; acc += wtot[w]; }
        }
        __syncthreads();
        int pre = wbase[wv] + inc - ssum;
        if (rank >= pre && rank < pre + ssum) {
            int rr = rank - pre;
            for (int i = 0; i < 4; ++i) {
                int h = hist[hbase + i];
                if (rr < h) { st = hbase + i; break; }
                rr -= h;
            }
        }
        __syncthreads();
    }
    const int pivot = (npiv << 12) | st;  // exact rank-127 key

    for (int t = tid; t < HW; t += 1024) {
        int k = nkey[t];
        if (k <= pivot) { int p = atomicAdd(&selc, 1); if (p < K_SEL) sel[p] = k; }
    }
    __syncthreads();

    // bitonic sort of the 128 selected keys (ascending; exactly 128 <= pivot)
    for (unsigned kk = 2; kk <= K_SEL; kk <<= 1) {
        for (unsigned j = kk >> 1; j > 0; j >>= 1) {
            if (tid < K_SEL) {
                unsigned ixj = tid ^ j;
                if (ixj > tid) {
                    int a = sel[tid], c = sel[ixj];
                    bool up = ((tid & kk) == 0);
                    if ((a > c) == up) { sel[tid] = c; sel[ixj] = a; }
                }
            }
            __syncthreads();
        }
    }

    if (tid < K_SEL) {
        int c;
        if (cnt >= K_SEL) c = sel[tid] & 0xFFF;
        else c = backup[b * K_SEL + tid];
        int cm = get_match(slotF, cposF, bb, c);
        int* o = out + dir * (NB * K_SEL * 2);
        o[(b * K_SEL + tid) * 2 + 0] = c;
        o[(b * K_SEL + tid) * 2 + 1] = cm;
    }
}

// ---------------------------------------------------------------------------
extern "C" void kernel_launch(void* const* d_in, const int* in_sizes, int n_in,
                              void* d_out, int out_size, void* d_ws, size_t ws_size,
                              hipStream_t stream) {
    const float* f1 = (const float*)d_in[0];
    const float* f2 = (const float*)d_in[1];
    const int* mask1 = (const int*)d_in[2];
    const int* mask2 = (const int*)d_in[3];
    const int* backup1 = (const int*)d_in[4];
    const int* backup2 = (const int*)d_in[5];
    int* out = (int*)d_out;

    char* ws = (char*)d_ws;
    char* tA = ws;                    ws += (size_t)NB * NRB * NKB * 2 * PAGE;
    char* tB = ws;                    ws += (size_t)NB * NRB * NKB * 2 * PAGE;
    u64* slot1 = (u64*)ws;            ws += (size_t)NB * HW * 8;
    u64* slot2 = (u64*)ws;            ws += (size_t)NB * HW * 8;
    float* sqc1 = (float*)ws;         ws += (size_t)NB * HW * 4;
    float* sqc2 = (float*)ws;         ws += (size_t)NB * HW * 4;
    int* vidx1 = (int*)ws;            ws += (size_t)NB * HW * 4;
    int* vidx2 = (int*)ws;            ws += (size_t)NB * HW * 4;
    int* cpos1 = (int*)ws;            ws += (size_t)NB * HW * 4;
    int* cpos2 = (int*)ws;            ws += (size_t)NB * HW * 4;
    int* cnts = (int*)ws;             ws += 256;

    compact_mask<<<dim3(NB, 2), 1024, 0, stream>>>(mask1, mask2,
                                                   vidx1, vidx2, cpos1, cpos2,
                                                   slot1, slot2, cnts);
    prep_tiles<<<dim3(NB * NRB, 2), 1024, 0, stream>>>(f1, f2, vidx1, vidx2,
                                                       cnts, sqc1, sqc2, tA, tB);
    gemm_argmin<<<dim3(1024, NB), 256, 0, stream>>>(tA, tB, sqc1, sqc2,
                                                    vidx1, vidx2, cnts,
                                                    slot1, slot2);
    topk_output<<<dim3(NB, 2), 1024, 0, stream>>>(slot1, slot2, cpos1, cpos2,
                                                  mask1, mask2, backup1, backup2,
                                                  out);
}